// Round 2
// baseline (12580.404 us; speedup 1.0000x reference)
//
#include <hip/hip_runtime.h>

#define HWp 9216
#define Wimg 96
#define Cfull 256

// ---------------- prep: weight transposes + effective 2x2 weights ----------------
__global__ __launch_bounds__(256) void k_prep(
    const float* __restrict__ hrW, const float* __restrict__ ceW,
    const float* __restrict__ repW3, const float* __restrict__ repW1,
    const float* __restrict__ supW,
    const float* __restrict__ c1W, const float* __restrict__ c2W,
    float* __restrict__ hrWt, float* __restrict__ ceWt,
    float* __restrict__ W3t, float* __restrict__ W1t,
    float* __restrict__ supWt, float* __restrict__ W1e, float* __restrict__ W2e)
{
    int idx = blockIdx.x * 256 + threadIdx.x;
    const int n0 = 16384;        // hrW (64,256)
    const int n1 = 14400;        // ceW (25,64,9)
    const int n2 = 3 * 65536;    // repW1 (3,256,256)
    const int n3 = 3 * 589824;   // repW3 (3,256,256,9)
    const int n4 = 589824;       // supW (256,256,9)
    const int n5 = 262144;       // Weff dst (ci,4,co)
    int i = idx;
    if (i < n0) { int co = i / 256, ci = i % 256; hrWt[ci * 64 + co] = hrW[i]; return; }
    i -= n0;
    if (i < n1) { int ko = i / 576, r = i % 576; ceWt[r * 25 + ko] = ceW[i]; return; }
    i -= n1;
    if (i < n2) { int blk = i / 65536, r = i % 65536; int co = r / 256, ci = r % 256;
                  W1t[blk * 65536 + ci * 256 + co] = repW1[i]; return; }
    i -= n2;
    if (i < n3) { int blk = i / 589824, r = i % 589824; int co = r / 2304, r2 = r % 2304;
                  W3t[blk * 589824 + r2 * 256 + co] = repW3[i]; return; }
    i -= n3;
    if (i < n4) { int co = i / 2304, r2 = i % 2304; supWt[r2 * 256 + co] = supW[i]; return; }
    i -= n4;
    if (i < 2 * n5) {
        const float* Wsrc = (i < n5) ? c1W : c2W;
        float* Wdst = (i < n5) ? W1e : W2e;
        int d = (i < n5) ? i : (i - n5);
        int co = d % 256; int ct = d / 256; int t = ct % 4; int ci = ct / 4;
        // tap order: (ym,xm),(ym,x),(y,xm),(y,x)
        float slh = (t & 1) ? -1.f : 1.f;            // [+1,-1,+1,-1]
        float shl = (t < 2) ? 1.f : -1.f;            // [+1,+1,-1,-1]
        float shh = (t == 0 || t == 3) ? 1.f : -1.f; // [+1,-1,-1,+1]
        float l = Wsrc[co * 768 + ci];
        float hlw = Wsrc[co * 768 + 256 + ci];
        float q = Wsrc[co * 768 + 512 + ci];
        Wdst[d] = 0.5f * (l * slh + hlw * shl + q * shh);
        return;
    }
}

// ---------------- guide = 1x1 conv 256->64 + bias ----------------
__global__ __launch_bounds__(256) void k_guide(const float* __restrict__ feat,
    const float* __restrict__ hrWt, const float* __restrict__ hrB,
    float* __restrict__ guide)
{
    int t = threadIdx.x;
    int b = blockIdx.x / 36, tile = blockIdx.x % 36;
    int p = tile * 256 + t;
    const float* fb = feat + (size_t)b * Cfull * HWp + p;
    float acc[64];
#pragma unroll
    for (int co = 0; co < 64; ++co) acc[co] = 0.f;
    for (int ci = 0; ci < 256; ++ci) {
        float v = fb[(size_t)ci * HWp];
        const float* w = hrWt + ci * 64;
#pragma unroll
        for (int co = 0; co < 64; ++co) acc[co] = fmaf(v, w[co], acc[co]);
    }
    float* gb = guide + (size_t)b * 64 * HWp + p;
#pragma unroll
    for (int co = 0; co < 64; ++co) gb[(size_t)co * HWp] = acc[co] + hrB[co];
}

// ---------------- mask = conv3x3 64->25 (pad1) + softmax over 25 ----------------
__global__ __launch_bounds__(256) void k_mask(const float* __restrict__ guide,
    const float* __restrict__ ceWt, const float* __restrict__ ceB,
    float* __restrict__ mask)
{
    int tt = threadIdx.x;
    int b = blockIdx.x / 36, tile = blockIdx.x % 36;
    int p = tile * 256 + tt, y = p / Wimg, x = p % Wimg;
    float acc[25];
#pragma unroll
    for (int k = 0; k < 25; ++k) acc[k] = ceB[k];
    const float* gb = guide + (size_t)b * 64 * HWp;
    for (int ci = 0; ci < 64; ++ci) {
        const float* gc = gb + (size_t)ci * HWp;
#pragma unroll
        for (int dy = 0; dy < 3; ++dy) {
            int yy = y + dy - 1;
#pragma unroll
            for (int dx = 0; dx < 3; ++dx) {
                int xx = x + dx - 1;
                float v = (yy >= 0 && yy < 96 && xx >= 0 && xx < 96) ? gc[yy * 96 + xx] : 0.f;
                const float* w = ceWt + (ci * 9 + dy * 3 + dx) * 25;
#pragma unroll
                for (int k = 0; k < 25; ++k) acc[k] = fmaf(v, w[k], acc[k]);
            }
        }
    }
    float m = acc[0];
#pragma unroll
    for (int k = 1; k < 25; ++k) m = fmaxf(m, acc[k]);
    float s = 0.f;
#pragma unroll
    for (int k = 0; k < 25; ++k) { acc[k] = __expf(acc[k] - m); s += acc[k]; }
    float inv = 1.f / s;
    float* mb = mask + (size_t)b * 25 * HWp + p;
#pragma unroll
    for (int k = 0; k < 25; ++k) mb[(size_t)k * HWp] = acc[k] * inv;
}

// ---------------- carafe: pred_up ----------------
__global__ __launch_bounds__(256) void k_carafe(const float* __restrict__ pred,
    const float* __restrict__ mask, float* __restrict__ pu_ws, float* __restrict__ pu_out)
{
    __shared__ float plds[2304];
    int t = threadIdx.x;
    int b = blockIdx.x / 36, tile = blockIdx.x % 36;
    const float* pb = pred + (size_t)b * 2304;
    for (int i = t; i < 2304; i += 256) plds[i] = pb[i];
    __syncthreads();
    int p = tile * 256 + t; int yy = p / 96, xx = p % 96;
    int sy = yy >> 1, sx = xx >> 1;
    int ry[5], rx[5];
#pragma unroll
    for (int i = 0; i < 5; ++i) {
        int r = sy + i - 2; if (r < 0) r = -r; if (r >= 48) r = 94 - r; ry[i] = r;
        int c = sx + i - 2; if (c < 0) c = -c; if (c >= 48) c = 94 - c; rx[i] = c;
    }
    const float* mb = mask + (size_t)b * 25 * HWp + p;
    float acc = 0.f;
#pragma unroll
    for (int i = 0; i < 5; ++i)
#pragma unroll
        for (int j = 0; j < 5; ++j)
            acc = fmaf(mb[(size_t)(i * 5 + j) * HWp], plds[ry[i] * 48 + rx[j]], acc);
    pu_ws[(size_t)b * HWp + p] = acc;
    pu_out[(size_t)b * HWp + p] = acc;
}

// ---------------- wh_in = feat * pred_up ----------------
__global__ __launch_bounds__(256) void k_whin(const float* __restrict__ feat,
    const float* __restrict__ pu, float* __restrict__ wh_in, int total4)
{
    int idx = blockIdx.x * 256 + threadIdx.x;
    if (idx >= total4) return;
    int p4 = idx % (HWp / 4);
    int rest = idx / (HWp / 4);
    int b = rest / Cfull;
    float4 f = ((const float4*)feat)[idx];
    float4 u = ((const float4*)pu)[(size_t)b * (HWp / 4) + p4];
    float4 o; o.x = f.x * u.x; o.y = f.y * u.y; o.z = f.z * u.z; o.w = f.w * u.w;
    ((float4*)wh_in)[idx] = o;
}

// ---- 2x2 conv 256->256 (haar-folded 1x1 of y) + bn + relu (+ optional +wh_in) ----
__global__ __launch_bounds__(256) void k_c2x2(const float* __restrict__ in,
    const float* __restrict__ Weff, const float* __restrict__ s, const float* __restrict__ bb,
    float* __restrict__ out, int fuse_add)
{
    int cog = blockIdx.x, tile = blockIdx.y, b = blockIdx.z;
    int ty = threadIdx.x >> 4, tx = threadIdx.x & 15;
    int y0 = (tile / 6) * 16, x0 = (tile % 6) * 16;
    __shared__ float ilds[16 * 289];
    float acc[32];
#pragma unroll
    for (int co = 0; co < 32; ++co) acc[co] = 0.f;
    const float* ib = in + (size_t)b * Cfull * HWp;
    for (int cc = 0; cc < 256; cc += 16) {
        __syncthreads();
        for (int i = threadIdx.x; i < 16 * 289; i += 256) {
            int ci = i / 289, r = i % 289, yy = r / 17, xx = r % 17;
            int gy = y0 + yy - 1; if (gy < 0) gy = 0;
            int gx = x0 + xx - 1; if (gx < 0) gx = 0;
            ilds[i] = ib[(size_t)(cc + ci) * HWp + gy * 96 + gx];
        }
        __syncthreads();
        for (int ci = 0; ci < 16; ++ci) {
            const float* tp = ilds + ci * 289;
            float v00 = tp[ty * 17 + tx], v01 = tp[ty * 17 + tx + 1];
            float v10 = tp[(ty + 1) * 17 + tx], v11 = tp[(ty + 1) * 17 + tx + 1];
            const float* w = Weff + (size_t)(cc + ci) * 1024 + cog * 32;
#pragma unroll
            for (int co = 0; co < 32; ++co)
                acc[co] += w[co] * v00 + w[256 + co] * v01 + w[512 + co] * v10 + w[768 + co] * v11;
        }
    }
    int p = (y0 + ty) * 96 + x0 + tx;
    size_t base = (size_t)b * Cfull * HWp + (size_t)(cog * 32) * HWp + p;
#pragma unroll
    for (int co = 0; co < 32; ++co) {
        int g = cog * 32 + co;
        float r = fmaxf(fmaf(acc[co], s[g], bb[g]), 0.f);
        size_t o = base + (size_t)co * HWp;
        if (fuse_add) r += in[o];   // + wh_in (same buffer as conv input)
        out[o] = r;
    }
}

// ---------------- rep block: conv3x3+bn+relu || conv1x1+bn+relu, sum, relu ----------------
__global__ __launch_bounds__(256) void k_rep(const float* __restrict__ in,
    const float* __restrict__ W3t, const float* __restrict__ W1t,
    const float* __restrict__ s3, const float* __restrict__ b3,
    const float* __restrict__ s1, const float* __restrict__ b1,
    const float* __restrict__ x2pw,
    float* __restrict__ out, int fuse_final)
{
    int cog = blockIdx.x, tile = blockIdx.y, b = blockIdx.z;
    int ty = threadIdx.x >> 4, tx = threadIdx.x & 15;
    int y0 = (tile / 6) * 16, x0 = (tile % 6) * 16;
    __shared__ float ilds[8 * 324];
    float a3[32], a1[32];
#pragma unroll
    for (int co = 0; co < 32; ++co) { a3[co] = 0.f; a1[co] = 0.f; }
    const float* ib = in + (size_t)b * Cfull * HWp;
    for (int cc = 0; cc < 256; cc += 8) {
        __syncthreads();
        for (int i = threadIdx.x; i < 8 * 324; i += 256) {
            int ci = i / 324, r = i % 324, yy = r / 18, xx = r % 18;
            int gy = y0 + yy - 1, gx = x0 + xx - 1;
            float v = 0.f;
            if (gy >= 0 && gy < 96 && gx >= 0 && gx < 96)
                v = ib[(size_t)(cc + ci) * HWp + gy * 96 + gx];
            ilds[i] = v;
        }
        __syncthreads();
        for (int ci = 0; ci < 8; ++ci) {
            const float* tp = ilds + ci * 324;
            float v[9];
#pragma unroll
            for (int dy = 0; dy < 3; ++dy)
#pragma unroll
                for (int dx = 0; dx < 3; ++dx)
                    v[dy * 3 + dx] = tp[(ty + dy) * 18 + tx + dx];
            const float* wb = W3t + (size_t)(cc + ci) * 2304 + cog * 32;
#pragma unroll
            for (int t = 0; t < 9; ++t) {
                float vv = v[t];
                const float* wt = wb + t * 256;
#pragma unroll
                for (int co = 0; co < 32; ++co) a3[co] = fmaf(wt[co], vv, a3[co]);
            }
            const float* w1b = W1t + (size_t)(cc + ci) * 256 + cog * 32;
            float vc = v[4];
#pragma unroll
            for (int co = 0; co < 32; ++co) a1[co] = fmaf(w1b[co], vc, a1[co]);
        }
    }
    int p = (y0 + ty) * 96 + x0 + tx;
    size_t base = (size_t)b * Cfull * HWp + (size_t)(cog * 32) * HWp + p;
#pragma unroll
    for (int co = 0; co < 32; ++co) {
        int g = cog * 32 + co;
        float r3 = fmaxf(fmaf(a3[co], s3[g], b3[g]), 0.f);
        float r1 = fmaxf(fmaf(a1[co], s1[g], b1[g]), 0.f);
        float r = fmaxf(r3 + r1, 0.f);
        size_t o = base + (size_t)co * HWp;
        if (fuse_final) r += x2pw[o];   // x2 + wh_in (pre-summed)
        out[o] = r;
    }
}

// ---------------- sup: conv3x3 + supCb, bn, relu, + feat -> d_out ----------------
__global__ __launch_bounds__(256) void k_sup(const float* __restrict__ in,
    const float* __restrict__ supWt, const float* __restrict__ cb,
    const float* __restrict__ ss, const float* __restrict__ sb,
    const float* __restrict__ feat, float* __restrict__ outp)
{
    int cog = blockIdx.x, tile = blockIdx.y, b = blockIdx.z;
    int ty = threadIdx.x >> 4, tx = threadIdx.x & 15;
    int y0 = (tile / 6) * 16, x0 = (tile % 6) * 16;
    __shared__ float ilds[8 * 324];
    float a3[32];
#pragma unroll
    for (int co = 0; co < 32; ++co) a3[co] = 0.f;
    const float* ib = in + (size_t)b * Cfull * HWp;
    for (int cc = 0; cc < 256; cc += 8) {
        __syncthreads();
        for (int i = threadIdx.x; i < 8 * 324; i += 256) {
            int ci = i / 324, r = i % 324, yy = r / 18, xx = r % 18;
            int gy = y0 + yy - 1, gx = x0 + xx - 1;
            float v = 0.f;
            if (gy >= 0 && gy < 96 && gx >= 0 && gx < 96)
                v = ib[(size_t)(cc + ci) * HWp + gy * 96 + gx];
            ilds[i] = v;
        }
        __syncthreads();
        for (int ci = 0; ci < 8; ++ci) {
            const float* tp = ilds + ci * 324;
            float v[9];
#pragma unroll
            for (int dy = 0; dy < 3; ++dy)
#pragma unroll
                for (int dx = 0; dx < 3; ++dx)
                    v[dy * 3 + dx] = tp[(ty + dy) * 18 + tx + dx];
            const float* wb = supWt + (size_t)(cc + ci) * 2304 + cog * 32;
#pragma unroll
            for (int t = 0; t < 9; ++t) {
                float vv = v[t];
                const float* wt = wb + t * 256;
#pragma unroll
                for (int co = 0; co < 32; ++co) a3[co] = fmaf(wt[co], vv, a3[co]);
            }
        }
    }
    int p = (y0 + ty) * 96 + x0 + tx;
    size_t base = (size_t)b * Cfull * HWp + (size_t)(cog * 32) * HWp + p;
#pragma unroll
    for (int co = 0; co < 32; ++co) {
        int g = cog * 32 + co;
        float r = fmaxf((a3[co] + cb[g]) * ss[g] + sb[g], 0.f);
        size_t o = base + (size_t)co * HWp;
        outp[o] = r + feat[o];
    }
}

// ---------------- pos logit: 1x1 conv 256->1 on out ----------------
__global__ __launch_bounds__(256) void k_pos(const float* __restrict__ outbuf,
    const float* __restrict__ posW, const float* __restrict__ posB, float* __restrict__ pos)
{
    int b = blockIdx.x / 36, tile = blockIdx.x % 36;
    int p = tile * 256 + threadIdx.x;
    const float* ob = outbuf + (size_t)b * Cfull * HWp + p;
    float acc = 0.f;
    for (int ci = 0; ci < 256; ++ci) acc = fmaf(ob[(size_t)ci * HWp], posW[ci], acc);
    pos[(size_t)b * HWp + p] = acc + posB[0];
}

extern "C" void kernel_launch(void* const* d_in, const int* in_sizes, int n_in,
                              void* d_out, int out_size, void* d_ws, size_t ws_size,
                              hipStream_t stream)
{
    const float* feat  = (const float*)d_in[0];
    const float* pred  = (const float*)d_in[1];
    const float* hrW   = (const float*)d_in[2];
    const float* hrB   = (const float*)d_in[3];
    const float* ceW   = (const float*)d_in[4];
    const float* ceB   = (const float*)d_in[5];
    const float* c1W   = (const float*)d_in[6];
    const float* c1s   = (const float*)d_in[7];
    const float* c1b   = (const float*)d_in[8];
    const float* c2W   = (const float*)d_in[9];
    const float* c2s   = (const float*)d_in[10];
    const float* c2b   = (const float*)d_in[11];
    const float* repW3 = (const float*)d_in[12];
    const float* repS3 = (const float*)d_in[13];
    const float* repB3 = (const float*)d_in[14];
    const float* repW1 = (const float*)d_in[15];
    const float* repS1 = (const float*)d_in[16];
    const float* repB1 = (const float*)d_in[17];
    const float* supW  = (const float*)d_in[18];
    const float* supCb = (const float*)d_in[19];
    const float* supS  = (const float*)d_in[20];
    const float* supB  = (const float*)d_in[21];
    const float* posW  = (const float*)d_in[22];
    const float* posB  = (const float*)d_in[23];

    float* ws = (float*)d_ws;
    const size_t A = 37748736;                 // B*C*H*W floats
    // weights/small header (13 MB)
    float* pred_up = ws;                       // 147456
    float* hrWt    = pred_up + 147456;         // 16384
    float* ceWt    = hrWt + 16384;             // 14400
    float* W1t     = ceWt + 14400;             // 196608
    float* W3t     = W1t + 196608;             // 1769472
    float* supWt   = W3t + 1769472;            // 589824
    float* W1e     = supWt + 589824;           // 262144
    float* W2e     = W1e + 262144;             // 262144  -> ends at 3258432
    float* buf0    = ws + 3258432;             // A floats
    float* buf1    = buf0 + A;                 // A floats  (total ws: 315 MB)
    float* guide   = buf1;                     // overlay (dead before buf1 = x2pw)
    float* maskb   = buf1 + 9437184;           // overlay

    float* out_main = (float*)d_out;           // used as ping-pong buffer too
    float* out_pos  = out_main + A;
    float* out_pu   = out_pos + 147456;

    dim3 gconv(8, 36, 16);
    k_prep<<<12153, 256, 0, stream>>>(hrW, ceW, repW3, repW1, supW, c1W, c2W,
                                      hrWt, ceWt, W3t, W1t, supWt, W1e, W2e);
    k_guide<<<576, 256, 0, stream>>>(feat, hrWt, hrB, guide);
    k_mask<<<576, 256, 0, stream>>>(guide, ceWt, ceB, maskb);
    k_carafe<<<576, 256, 0, stream>>>(pred, maskb, pred_up, out_pu);
    k_whin<<<36864, 256, 0, stream>>>(feat, pred_up, buf0, 9437184);      // wh_in -> buf0
    k_c2x2<<<gconv, 256, 0, stream>>>(buf0, W1e, c1s, c1b, out_main, 0);  // xA -> d_out
    k_c2x2<<<gconv, 256, 0, stream>>>(buf0, W2e, c2s, c2b, buf1, 1);      // x2+wh_in -> buf1
    k_rep<<<gconv, 256, 0, stream>>>(out_main, W3t, W1t, repS3, repB3, repS1, repB1,
                                     buf1, buf0, 0);                       // rep1 -> buf0
    k_rep<<<gconv, 256, 0, stream>>>(buf0, W3t + 589824, W1t + 65536,
                                     repS3 + 256, repB3 + 256, repS1 + 256, repB1 + 256,
                                     buf1, out_main, 0);                   // rep2 -> d_out
    k_rep<<<gconv, 256, 0, stream>>>(out_main, W3t + 2 * 589824, W1t + 2 * 65536,
                                     repS3 + 512, repB3 + 512, repS1 + 512, repB1 + 512,
                                     buf1, buf0, 1);                       // rep3(+x2pw) -> buf0
    k_sup<<<gconv, 256, 0, stream>>>(buf0, supWt, supCb, supS, supB, feat, out_main);
    k_pos<<<576, 256, 0, stream>>>(out_main, posW, posB, out_pos);
}